// Round 14
// baseline (438.516 us; speedup 1.0000x reference)
//
#include <hip/hip_runtime.h>

#if __has_builtin(__builtin_amdgcn_exp2f)
#define EXP2F(x) __builtin_amdgcn_exp2f(x)
#else
#define EXP2F(x) exp2f(x)
#endif
#if __has_builtin(__builtin_amdgcn_rcpf)
#define RCPF(x) __builtin_amdgcn_rcpf(x)
#else
#define RCPF(x) (1.0f / (x))
#endif

namespace {

constexpr int B_ = 2048, T_ = 512, D_ = 8, H_ = 20, L_ = 10;
constexpr int NG    = 16;        // batch group per block (MFMA N)
constexpr int PADK  = 24;        // shorts per [batch] h row (48B)
constexpr int NW    = 11;        // 10 layer waves + 1 head wave
constexpr int NTHR  = NW * 64;   // 704
constexpr int DEPTH = 8;         // h ring depth
constexpr int SLOT_STRIDE  = L_ * NG * PADK;  // 3840 shorts
constexpr int LAYER_STRIDE = NG * PADK;       // 384 shorts

typedef float f32x4 __attribute__((ext_vector_type(4)));
typedef short s16x4 __attribute__((ext_vector_type(4)));  // 4 bf16, 2 VGPRs

#define LD4(p) (*reinterpret_cast<const f32x4*>(p))

__device__ __forceinline__ unsigned short f2bf(float f) {
    unsigned u = __builtin_bit_cast(unsigned, f);
    return (unsigned short)((u + 0x7FFFu + ((u >> 16) & 1u)) >> 16);
}
__device__ __forceinline__ float bf2f(unsigned short b) {
    return __builtin_bit_cast(float, (unsigned)b << 16);
}
__device__ __forceinline__ unsigned cvt_pk_bf16(float s0, float s1) {
    unsigned r;
    asm("v_cvt_pk_bf16_f32 %0, %1, %2" : "=v"(r) : "v"(s0), "v"(s1));
    return r;
}
__device__ __forceinline__ float tanh_fast(float x) {
    float e = EXP2F(x * 2.8853900817779268f);
    return fmaf(-2.0f, RCPF(1.0f + e), 1.0f);
}

// K=16 MFMA: B-frag layout == D layout -> h_next (pw,qw) IS next step's
// B operand (validated R12: absmax 6.7e-4).
__device__ __forceinline__ f32x4 mfma16(s16x4 a, s16x4 b, f32x4 c) {
    asm("v_mfma_f32_16x16x16_bf16 %0, %1, %2, %0"
        : "+v"(c) : "v"(a), "v"(b));
    return c;
}

struct AF { s16x4 hi, lo; };
__device__ __forceinline__ AF mkfrag(float v0, float v1, float v2, float v3) {
    AF f; float v[4] = {v0, v1, v2, v3};
    #pragma unroll
    for (int e = 0; e < 4; ++e) {
        unsigned short h = f2bf(v[e]);
        f.hi[e] = (short)h; f.lo[e] = (short)f2bf(v[e] - bf2f(h));
    }
    return f;
}

// bare acquire-poll (R12: s_sleep backoff adds wake latency -> regression)
__device__ __forceinline__ int wait_ge_ret(int* p, int v) {
    int cur = __hip_atomic_load(p, __ATOMIC_ACQUIRE, __HIP_MEMORY_SCOPE_WORKGROUP);
    while (cur < v)
        cur = __hip_atomic_load(p, __ATOMIC_ACQUIRE, __HIP_MEMORY_SCOPE_WORKGROUP);
    __builtin_amdgcn_sched_barrier(0);
    return cur;
}
__device__ __forceinline__ void publish(int* p, int v) {
    asm volatile("s_waitcnt lgkmcnt(0)" ::: "memory");
    __hip_atomic_store(p, v, __ATOMIC_RELAXED, __HIP_MEMORY_SCOPE_WORKGROUP);
}

__device__ __forceinline__ s16x4 pack_x4(f32x4 a, f32x4 b, int g) {
    s16x4 r;
    #pragma unroll
    for (int e = 0; e < 4; ++e) {
        int k = ((g & 1) << 2) + e;
        float f = (k < 4) ? a[k] : b[k - 4];
        unsigned short h = f2bf(f);
        r[e] = (short)((g < 2) ? h : f2bf(f - bf2f(h)));
    }
    return r;
}

// R14 = R13 with the x-ring bug fixed. R13's failure: 6-slot ring consuming
// 2/iter must REFILL times t+6,t+7; it loaded t+4,t+5 -> from t=6 wave 0
// consumed stale x (t-2), absmax 7.9e-3. Structure unchanged:
// (1) t-loop unrolled x2 (one poll/WAR/publish per 2 steps, B0 reads paired);
// (2) parallel MFMA trees: pre (B0-only) + 2x2 h-dependent chains + add-tree;
// (3) reg-resident own-h via K=16 D->B identity.
__global__ __launch_bounds__(NTHR) void rnn_async(
    const float* __restrict__ x,      const float* __restrict__ w_ih0,
    const float* __restrict__ w_ih,   const float* __restrict__ w_hh,
    const float* __restrict__ b_ih,   const float* __restrict__ b_hh,
    const float* __restrict__ fc_w,   const float* __restrict__ fc_b,
    const float* __restrict__ l2_w,   const float* __restrict__ l2_b,
    float* __restrict__ out)          // [B,T] flat
{
    __shared__ __align__(16) unsigned short h_lds[DEPTH][L_][NG][PADK]; // 61.4KB
    __shared__ int prog[16];

    const int tid = threadIdx.x;
    const int w   = tid >> 6;       // 0..9 layer wave, 10 head
    const int l   = tid & 63;
    const int col = l & 15;
    const int g   = l >> 4;
    const int bg  = blockIdx.x * NG;

    {   // zero ring (h0=0; pad shorts stay 0) + prog
        uint4* p4 = reinterpret_cast<uint4*>(&h_lds[0][0][0][0]);
        for (int i = tid; i < DEPTH * SLOT_STRIDE / 8; i += NTHR)
            p4[i] = make_uint4(0, 0, 0, 0);
        if (tid < 16) prog[tid] = 0;
    }

    // ---- weight fragments (identical to validated R12) ----
    AF iA0, iA1, iB0, iB1, hA0, hA1, hB0, hB1;
    f32x4 bias0 = {0.f,0.f,0.f,0.f}, bias1 = bias0, l2v0 = bias0, l2v1 = bias0;
    float l2bv = 0.f;
    const bool m1ok = col < 4;
    const int k0 = g * 4;

    if (w < L_) {
        if (w == 0) {
            const int kx = ((g & 1) << 2);
            const float* r0 = w_ih0 + col * D_ + kx;
            iA0 = mkfrag(r0[0], r0[1], r0[2], r0[3]);
            const float* r1 = w_ih0 + (16 + col) * D_ + kx;
            iA1 = m1ok ? mkfrag(r1[0], r1[1], r1[2], r1[3]) : mkfrag(0,0,0,0);
            iB0 = mkfrag(0,0,0,0); iB1 = mkfrag(0,0,0,0);
        } else {
            const float* Wm0 = w_ih + ((w - 1) * H_ + col) * H_;
            const float* Wm1 = w_ih + ((w - 1) * H_ + 16 + col) * H_;
            iA0 = mkfrag(Wm0[k0], Wm0[k0+1], Wm0[k0+2], Wm0[k0+3]);
            iA1 = m1ok ? mkfrag(Wm1[k0], Wm1[k0+1], Wm1[k0+2], Wm1[k0+3])
                       : mkfrag(0,0,0,0);
            iB0 = (g == 0) ? mkfrag(Wm0[16], Wm0[17], Wm0[18], Wm0[19])
                           : mkfrag(0,0,0,0);
            iB1 = (g == 0 && m1ok)
                           ? mkfrag(Wm1[16], Wm1[17], Wm1[18], Wm1[19])
                           : mkfrag(0,0,0,0);
        }
        const float* Um0 = w_hh + (w * H_ + col) * H_;
        const float* Um1 = w_hh + (w * H_ + 16 + col) * H_;
        hA0 = mkfrag(Um0[k0], Um0[k0+1], Um0[k0+2], Um0[k0+3]);
        hA1 = m1ok ? mkfrag(Um1[k0], Um1[k0+1], Um1[k0+2], Um1[k0+3])
                   : mkfrag(0,0,0,0);
        hB0 = (g == 0) ? mkfrag(Um0[16], Um0[17], Um0[18], Um0[19])
                       : mkfrag(0,0,0,0);
        hB1 = (g == 0 && m1ok) ? mkfrag(Um1[16], Um1[17], Um1[18], Um1[19])
                               : mkfrag(0,0,0,0);
        #pragma unroll
        for (int r = 0; r < 4; ++r) {
            const int row = g * 4 + r;
            bias0[r] = b_ih[w * H_ + row] + b_hh[w * H_ + row];
            bias1[r] = (g == 0) ? (b_ih[w * H_ + 16 + r] +
                                   b_hh[w * H_ + 16 + r]) : 0.f;
        }
    } else {
        const float* Fm0 = fc_w + col * H_;
        const float* Fm1 = fc_w + (16 + col) * H_;
        iA0 = mkfrag(Fm0[k0], Fm0[k0+1], Fm0[k0+2], Fm0[k0+3]);
        iA1 = m1ok ? mkfrag(Fm1[k0], Fm1[k0+1], Fm1[k0+2], Fm1[k0+3])
                   : mkfrag(0,0,0,0);
        iB0 = (g == 0) ? mkfrag(Fm0[16], Fm0[17], Fm0[18], Fm0[19])
                       : mkfrag(0,0,0,0);
        iB1 = (g == 0 && m1ok) ? mkfrag(Fm1[16], Fm1[17], Fm1[18], Fm1[19])
                               : mkfrag(0,0,0,0);
        hA0 = hA1 = hB0 = hB1 = mkfrag(0,0,0,0);
        #pragma unroll
        for (int r = 0; r < 4; ++r) {
            bias0[r] = fc_b[g * 4 + r];
            bias1[r] = (g == 0) ? fc_b[16 + r] : 0.f;
            l2v0[r]  = l2_w[g * 4 + r];
            l2v1[r]  = (g == 0) ? l2_w[16 + r] : 0.f;
        }
        l2bv = l2_b[0];
    }

    // wave-0 x prefetch ring: 6 packed slots = times t..t+5
    s16x4 xp0 = {0,0,0,0}, xp1 = xp0, xp2 = xp0, xp3 = xp0, xp4 = xp0, xp5 = xp0;
    if (w == 0) {
        const float* xp = x + (size_t)(bg + col) * T_ * D_;
        xp0 = pack_x4(LD4(xp),          LD4(xp + 4), g);
        xp1 = pack_x4(LD4(xp + D_),     LD4(xp + D_ + 4), g);
        xp2 = pack_x4(LD4(xp + 2 * D_), LD4(xp + 2 * D_ + 4), g);
        xp3 = pack_x4(LD4(xp + 3 * D_), LD4(xp + 3 * D_ + 4), g);
        xp4 = pack_x4(LD4(xp + 4 * D_), LD4(xp + 4 * D_ + 4), g);
        xp5 = pack_x4(LD4(xp + 5 * D_), LD4(xp + 5 * D_ + 4), g);
    }

    __syncthreads();  // ONLY barrier

    unsigned short* const hb = &h_lds[0][0][0][0];
    const f32x4 z4 = {0.f, 0.f, 0.f, 0.f};
    const s16x4 zb = {0, 0, 0, 0};

    if (w < L_) {
        const int rdB0 = (w ? (w - 1) * LAYER_STRIDE : 0) + col * PADK;
        const int wr0  = w * LAYER_STRIDE + col * PADK + g * 4;
        const int wr1  = w * LAYER_STRIDE + col * PADK + 16;
        uint2 pw = make_uint2(0u, 0u), qw = pw;   // h[t-1] == next B1 frags
        int p_up = 0, p_dn = 0;
        for (int t = 0; t < T_; t += 2) {
            const int sc0 = (t & (DEPTH - 1)) * SLOT_STRIDE;
            const int sc1 = ((t + 1) & (DEPTH - 1)) * SLOT_STRIDE;
            // ---- inputs for BOTH steps (one poll, overlapped reads) ----
            s16x4 b0a0, b0a1, b0b0, b0b1;
            if (w == 0) {
                b0a0 = xp0; b0a1 = zb; b0b0 = xp1; b0b1 = zb;
                xp0 = xp2; xp1 = xp3; xp2 = xp4; xp3 = xp5;
                // FIX (R13 bug): refill = times t+6, t+7 (was t+4 -> stale x)
                const float* xq = x + ((size_t)(bg + col) * T_ + t + 6) * D_;
                if (t + 6 < T_) xp4 = pack_x4(LD4(xq), LD4(xq + 4), g);
                if (t + 7 < T_) xp5 = pack_x4(LD4(xq + D_), LD4(xq + D_ + 4), g);
            } else {
                if (p_up < t + 2) p_up = wait_ge_ret(&prog[w - 1], t + 2);
                const unsigned short* rp0 = hb + sc0 + rdB0;
                const unsigned short* rp1 = hb + sc1 + rdB0;
                b0a0 = __builtin_bit_cast(s16x4,
                        *reinterpret_cast<const uint2*>(rp0 + g * 4));
                b0b0 = __builtin_bit_cast(s16x4,
                        *reinterpret_cast<const uint2*>(rp1 + g * 4));
                b0a1 = (g == 0) ? __builtin_bit_cast(s16x4,
                        *reinterpret_cast<const uint2*>(rp0 + 16)) : zb;
                b0b1 = (g == 0) ? __builtin_bit_cast(s16x4,
                        *reinterpret_cast<const uint2*>(rp1 + 16)) : zb;
            }
            // WAR once: slots (t&7),(t+1&7) reused from t-8,t-7
            if (t >= DEPTH && p_dn < t + 2 - DEPTH)
                p_dn = wait_ge_ret(&prog[w + 1], t + 2 - DEPTH);

            // ================= step A (time t) =================
            {
                const s16x4 b1k0 = __builtin_bit_cast(s16x4, pw);
                const s16x4 b1k1 = __builtin_bit_cast(s16x4, qw);
                f32x4 pre0 = mfma16(iA0.hi, b0a0, bias0);
                pre0 = mfma16(iA0.lo, b0a0, pre0);
                f32x4 pre1 = mfma16(iA1.hi, b0a0, bias1);
                pre1 = mfma16(iA1.lo, b0a0, pre1);
                if (w != 0) {
                    pre0 = mfma16(iB0.hi, b0a1, pre0);
                    pre0 = mfma16(iB0.lo, b0a1, pre0);
                    pre1 = mfma16(iB1.hi, b0a1, pre1);
                    pre1 = mfma16(iB1.lo, b0a1, pre1);
                }
                f32x4 s10 = mfma16(hA0.hi, b1k0, z4);
                s10 = mfma16(hA0.lo, b1k0, s10);
                f32x4 s20 = mfma16(hB0.hi, b1k1, z4);
                s20 = mfma16(hB0.lo, b1k1, s20);
                f32x4 s11 = mfma16(hA1.hi, b1k0, z4);
                s11 = mfma16(hA1.lo, b1k0, s11);
                f32x4 s21 = mfma16(hB1.hi, b1k1, z4);
                s21 = mfma16(hB1.lo, b1k1, s21);
                f32x4 acc0 = (pre0 + s10) + s20;
                f32x4 acc1 = (pre1 + s11) + s21;
                pw.x = cvt_pk_bf16(tanh_fast(acc0[0]),  tanh_fast(acc0[1]));
                pw.y = cvt_pk_bf16(tanh_fast(acc0[2]),  tanh_fast(acc0[3]));
                qw.x = cvt_pk_bf16(tanh_fast(acc1[0]),  tanh_fast(acc1[1]));
                qw.y = cvt_pk_bf16(tanh_fast(acc1[2]),  tanh_fast(acc1[3]));
                *reinterpret_cast<uint2*>(hb + sc0 + wr0) = pw;
                if (g == 0) *reinterpret_cast<uint2*>(hb + sc0 + wr1) = qw;
            }
            // ================= step B (time t+1) =================
            {
                const s16x4 b1k0 = __builtin_bit_cast(s16x4, pw);
                const s16x4 b1k1 = __builtin_bit_cast(s16x4, qw);
                f32x4 pre0 = mfma16(iA0.hi, b0b0, bias0);
                pre0 = mfma16(iA0.lo, b0b0, pre0);
                f32x4 pre1 = mfma16(iA1.hi, b0b0, bias1);
                pre1 = mfma16(iA1.lo, b0b0, pre1);
                if (w != 0) {
                    pre0 = mfma16(iB0.hi, b0b1, pre0);
                    pre0 = mfma16(iB0.lo, b0b1, pre0);
                    pre1 = mfma16(iB1.hi, b0b1, pre1);
                    pre1 = mfma16(iB1.lo, b0b1, pre1);
                }
                f32x4 s10 = mfma16(hA0.hi, b1k0, z4);
                s10 = mfma16(hA0.lo, b1k0, s10);
                f32x4 s20 = mfma16(hB0.hi, b1k1, z4);
                s20 = mfma16(hB0.lo, b1k1, s20);
                f32x4 s11 = mfma16(hA1.hi, b1k0, z4);
                s11 = mfma16(hA1.lo, b1k0, s11);
                f32x4 s21 = mfma16(hB1.hi, b1k1, z4);
                s21 = mfma16(hB1.lo, b1k1, s21);
                f32x4 acc0 = (pre0 + s10) + s20;
                f32x4 acc1 = (pre1 + s11) + s21;
                pw.x = cvt_pk_bf16(tanh_fast(acc0[0]),  tanh_fast(acc0[1]));
                pw.y = cvt_pk_bf16(tanh_fast(acc0[2]),  tanh_fast(acc0[3]));
                qw.x = cvt_pk_bf16(tanh_fast(acc1[0]),  tanh_fast(acc1[1]));
                qw.y = cvt_pk_bf16(tanh_fast(acc1[2]),  tanh_fast(acc1[3]));
                *reinterpret_cast<uint2*>(hb + sc1 + wr0) = pw;
                if (g == 0) *reinterpret_cast<uint2*>(hb + sc1 + wr1) = qw;
            }
            if (l == 0) publish(&prog[w], t + 2);
        }
    } else {
        // head wave: y[t], y[t+1] from h[9] (no self-dependency)
        const int rdH = (L_ - 1) * LAYER_STRIDE + col * PADK;
        int p_up = 0;
        for (int t = 0; t < T_; t += 2) {
            if (p_up < t + 2) p_up = wait_ge_ret(&prog[L_ - 1], t + 2);
            const unsigned short* rp0 =
                hb + (t & (DEPTH - 1)) * SLOT_STRIDE + rdH;
            const unsigned short* rp1 =
                hb + ((t + 1) & (DEPTH - 1)) * SLOT_STRIDE + rdH;
            #pragma unroll
            for (int s = 0; s < 2; ++s) {
                const unsigned short* rp = s ? rp1 : rp0;
                s16x4 bt0 = __builtin_bit_cast(s16x4,
                        *reinterpret_cast<const uint2*>(rp + g * 4));
                s16x4 bt1 = (g == 0) ? __builtin_bit_cast(s16x4,
                        *reinterpret_cast<const uint2*>(rp + 16)) : zb;
                f32x4 z0 = mfma16(iA0.hi, bt0, bias0);
                z0 = mfma16(iA0.lo, bt0, z0);
                f32x4 z0b = mfma16(iB0.hi, bt1, z4);
                z0b = mfma16(iB0.lo, bt1, z0b);
                f32x4 z1 = mfma16(iA1.hi, bt0, bias1);
                z1 = mfma16(iA1.lo, bt0, z1);
                f32x4 z1b = mfma16(iB1.hi, bt1, z4);
                z1b = mfma16(iB1.lo, bt1, z1b);
                z0 += z0b; z1 += z1b;
                float part = 0.f;
                #pragma unroll
                for (int r = 0; r < 4; ++r) {
                    part = fmaf(l2v0[r], fmaxf(z0[r], 0.f), part);
                    part = fmaf(l2v1[r], fmaxf(z1[r], 0.f), part);
                }
                part += __shfl_xor(part, 16);
                part += __shfl_xor(part, 32);
                if (l < NG) out[(size_t)(bg + l) * T_ + t + s] = part + l2bv;
            }
            if (l == 0) publish(&prog[L_], t + 2);
        }
    }
}

}  // namespace

extern "C" void kernel_launch(void* const* d_in, const int* in_sizes, int n_in,
                              void* d_out, int out_size, void* d_ws, size_t ws_size,
                              hipStream_t stream) {
    const float* x     = (const float*)d_in[0];
    const float* w_ih0 = (const float*)d_in[1];
    const float* w_ih  = (const float*)d_in[2];
    const float* w_hh  = (const float*)d_in[3];
    const float* b_ih  = (const float*)d_in[4];
    const float* b_hh  = (const float*)d_in[5];
    const float* fc_w  = (const float*)d_in[6];
    const float* fc_b  = (const float*)d_in[7];
    const float* l2_w  = (const float*)d_in[8];
    const float* l2_b  = (const float*)d_in[9];
    float* out = (float*)d_out;

    const int grid = B_ / NG;  // 128
    hipLaunchKernelGGL(rnn_async, dim3(grid), dim3(NTHR), 0, stream,
                       x, w_ih0, w_ih, w_hh, b_ih, b_hh, fc_w, fc_b,
                       l2_w, l2_b, out);
}

// Round 16
// 317.153 us; speedup vs baseline: 1.3827x; 1.3827x over previous
//
#include <hip/hip_runtime.h>

#if __has_builtin(__builtin_amdgcn_exp2f)
#define EXP2F(x) __builtin_amdgcn_exp2f(x)
#else
#define EXP2F(x) exp2f(x)
#endif
#if __has_builtin(__builtin_amdgcn_rcpf)
#define RCPF(x) __builtin_amdgcn_rcpf(x)
#else
#define RCPF(x) (1.0f / (x))
#endif

namespace {

constexpr int B_ = 2048, T_ = 512, D_ = 8, H_ = 20, L_ = 10;
constexpr int NG    = 16;        // batch group per block (MFMA N)
constexpr int PADK  = 24;        // f16 elems per [batch] h row (48B)
constexpr int NW    = 11;        // 10 layer waves + 1 head wave
constexpr int NTHR  = NW * 64;   // 704
constexpr int DEPTH = 8;         // h ring depth
constexpr int SLOT_STRIDE  = L_ * NG * PADK;  // 3840 shorts
constexpr int LAYER_STRIDE = NG * PADK;       // 384 shorts

typedef float    f32x4 __attribute__((ext_vector_type(4)));
typedef _Float16 f16x4 __attribute__((ext_vector_type(4)));  // 2 VGPRs

#define LD4(p) (*reinterpret_cast<const f32x4*>(p))

__device__ __forceinline__ unsigned pack2h(float a, float b) {
    unsigned short ua = __builtin_bit_cast(unsigned short, (_Float16)a);
    unsigned short ub = __builtin_bit_cast(unsigned short, (_Float16)b);
    return (unsigned)ua | ((unsigned)ub << 16);
}
__device__ __forceinline__ float tanh_fast(float x) {
    float e = EXP2F(x * 2.8853900817779268f);
    return fmaf(-2.0f, RCPF(1.0f + e), 1.0f);
}

// K=16 f16 MFMA. B-frag layout == D layout (validated R12 via bf16 twin:
// absmax 6.7e-4) -> h_next packed f16 IS next step's B operand.
// NOTE spelling: legacy f16 K=16 builtin has NO underscore before f16
// (R15 compile error; compiler fix-it: __builtin_amdgcn_mfma_f32_16x16x16f16).
__device__ __forceinline__ f32x4 mfma16h(f16x4 a, f16x4 b, f32x4 c) {
    return __builtin_amdgcn_mfma_f32_16x16x16f16(a, b, c, 0, 0, 0);
}

__device__ __forceinline__ f16x4 mkfragh(float v0, float v1, float v2, float v3) {
    f16x4 f;
    f[0] = (_Float16)v0; f[1] = (_Float16)v1;
    f[2] = (_Float16)v2; f[3] = (_Float16)v3;
    return f;
}

// bare acquire-poll, returns freshest value (register caching); no s_sleep
// (R12 lesson: backoff adds wake latency to the handoff)
__device__ __forceinline__ int wait_ge_ret(int* p, int v) {
    int cur = __hip_atomic_load(p, __ATOMIC_ACQUIRE, __HIP_MEMORY_SCOPE_WORKGROUP);
    while (cur < v)
        cur = __hip_atomic_load(p, __ATOMIC_ACQUIRE, __HIP_MEMORY_SCOPE_WORKGROUP);
    __builtin_amdgcn_sched_barrier(0);
    return cur;
}
__device__ __forceinline__ void publish(int* p, int v) {
    asm volatile("s_waitcnt lgkmcnt(0)" ::: "memory");
    __hip_atomic_store(p, v, __ATOMIC_RELAXED, __HIP_MEMORY_SCOPE_WORKGROUP);
}

// x B-frag, K-cols 0..7 = x in f16 (hi), 8..15 = f32 residual (lo): exact x.
// lane(col,g) holds k = g*4+e.
__device__ __forceinline__ f16x4 pack_x4h(f32x4 a, f32x4 b, int g) {
    f16x4 r;
    #pragma unroll
    for (int e = 0; e < 4; ++e) {
        const int k = g * 4 + e;
        const int el = k & 7;
        float f = (el < 4) ? a[el] : b[el - 4];
        _Float16 hi = (_Float16)f;
        r[e] = (k < 8) ? hi : (_Float16)(f - (float)hi);
    }
    return r;
}

// R16 = R15 with the builtin spelling fixed. Theory unchanged: cut per-step
// issue work. R8-R14 (7 structures) all 357-438us; shared component =
// instruction issue (~480cy/step = 29% VALUBusy). f16 single frags halve
// MFMA (16->8/step), drop add-trees, halve frag regs. h carried f16
// (quantization 8x finer than bf16) offsets f16-weight rounding. Skeleton =
// R12 (single-step loop, DEPTH=8 ring, cached polls).
__global__ __launch_bounds__(NTHR) void rnn_async(
    const float* __restrict__ x,      const float* __restrict__ w_ih0,
    const float* __restrict__ w_ih,   const float* __restrict__ w_hh,
    const float* __restrict__ b_ih,   const float* __restrict__ b_hh,
    const float* __restrict__ fc_w,   const float* __restrict__ fc_b,
    const float* __restrict__ l2_w,   const float* __restrict__ l2_b,
    float* __restrict__ out)          // [B,T] flat
{
    __shared__ __align__(16) unsigned short h_lds[DEPTH][L_][NG][PADK]; // 61.4KB
    __shared__ int prog[16];

    const int tid = threadIdx.x;
    const int w   = tid >> 6;       // 0..9 layer wave, 10 head
    const int l   = tid & 63;
    const int col = l & 15;         // batch (B,D) / weight row m (A)
    const int g   = l >> 4;         // k-group (B) / row-group (D)
    const int bg  = blockIdx.x * NG;

    {   // zero ring (h0=0; pad stays 0) + prog
        uint4* p4 = reinterpret_cast<uint4*>(&h_lds[0][0][0][0]);
        for (int i = tid; i < DEPTH * SLOT_STRIDE / 8; i += NTHR)
            p4[i] = make_uint4(0, 0, 0, 0);
        if (tid < 16) prog[tid] = 0;
    }

    // ---- f16 weight fragments: A(m, k=g*4+e) ----
    f16x4 iA0, iA1, iB0, iB1, hA0, hA1, hB0, hB1;
    f32x4 bias0 = {0.f,0.f,0.f,0.f}, bias1 = bias0, l2v0 = bias0, l2v1 = bias0;
    float l2bv = 0.f;
    const bool m1ok = col < 4;      // Mtile1 rows 16+col valid
    const int k0 = g * 4;
    const f16x4 zh = {(_Float16)0.f, (_Float16)0.f, (_Float16)0.f, (_Float16)0.f};

    if (w < L_) {
        if (w == 0) {               // A[m][k] = w_ih0[m][k&7] (hi & lo cols)
            const int kx = k0 & 7;  // g0:0 g1:4 g2:0 g3:4
            const float* r0 = w_ih0 + col * D_ + kx;
            iA0 = mkfragh(r0[0], r0[1], r0[2], r0[3]);
            const float* r1 = w_ih0 + (16 + col) * D_ + kx;
            iA1 = m1ok ? mkfragh(r1[0], r1[1], r1[2], r1[3]) : zh;
            iB0 = zh; iB1 = zh;
        } else {
            const float* Wm0 = w_ih + ((w - 1) * H_ + col) * H_;
            const float* Wm1 = w_ih + ((w - 1) * H_ + 16 + col) * H_;
            iA0 = mkfragh(Wm0[k0], Wm0[k0+1], Wm0[k0+2], Wm0[k0+3]);
            iA1 = m1ok ? mkfragh(Wm1[k0], Wm1[k0+1], Wm1[k0+2], Wm1[k0+3]) : zh;
            iB0 = (g == 0) ? mkfragh(Wm0[16], Wm0[17], Wm0[18], Wm0[19]) : zh;
            iB1 = (g == 0 && m1ok)
                           ? mkfragh(Wm1[16], Wm1[17], Wm1[18], Wm1[19]) : zh;
        }
        const float* Um0 = w_hh + (w * H_ + col) * H_;
        const float* Um1 = w_hh + (w * H_ + 16 + col) * H_;
        hA0 = mkfragh(Um0[k0], Um0[k0+1], Um0[k0+2], Um0[k0+3]);
        hA1 = m1ok ? mkfragh(Um1[k0], Um1[k0+1], Um1[k0+2], Um1[k0+3]) : zh;
        hB0 = (g == 0) ? mkfragh(Um0[16], Um0[17], Um0[18], Um0[19]) : zh;
        hB1 = (g == 0 && m1ok) ? mkfragh(Um1[16], Um1[17], Um1[18], Um1[19]) : zh;
        #pragma unroll
        for (int r = 0; r < 4; ++r) {
            const int row = g * 4 + r;
            bias0[r] = b_ih[w * H_ + row] + b_hh[w * H_ + row];
            bias1[r] = (g == 0) ? (b_ih[w * H_ + 16 + r] +
                                   b_hh[w * H_ + 16 + r]) : 0.f;
        }
    } else {
        const float* Fm0 = fc_w + col * H_;
        const float* Fm1 = fc_w + (16 + col) * H_;
        iA0 = mkfragh(Fm0[k0], Fm0[k0+1], Fm0[k0+2], Fm0[k0+3]);
        iA1 = m1ok ? mkfragh(Fm1[k0], Fm1[k0+1], Fm1[k0+2], Fm1[k0+3]) : zh;
        iB0 = (g == 0) ? mkfragh(Fm0[16], Fm0[17], Fm0[18], Fm0[19]) : zh;
        iB1 = (g == 0 && m1ok) ? mkfragh(Fm1[16], Fm1[17], Fm1[18], Fm1[19]) : zh;
        hA0 = hA1 = hB0 = hB1 = zh;
        #pragma unroll
        for (int r = 0; r < 4; ++r) {
            bias0[r] = fc_b[g * 4 + r];
            bias1[r] = (g == 0) ? fc_b[16 + r] : 0.f;
            l2v0[r]  = l2_w[g * 4 + r];
            l2v1[r]  = (g == 0) ? l2_w[16 + r] : 0.f;
        }
        l2bv = l2_b[0];
    }

    // wave-0 x prefetch ring: 4 packed slots = times t..t+3
    f16x4 xp0 = zh, xp1 = zh, xp2 = zh, xp3 = zh;
    if (w == 0) {
        const float* xp = x + (size_t)(bg + col) * T_ * D_;
        xp0 = pack_x4h(LD4(xp),          LD4(xp + 4), g);
        xp1 = pack_x4h(LD4(xp + D_),     LD4(xp + D_ + 4), g);
        xp2 = pack_x4h(LD4(xp + 2 * D_), LD4(xp + 2 * D_ + 4), g);
        xp3 = pack_x4h(LD4(xp + 3 * D_), LD4(xp + 3 * D_ + 4), g);
    }

    __syncthreads();  // ONLY barrier

    unsigned short* const hb = &h_lds[0][0][0][0];

    if (w < L_) {
        const int rdB0 = (w ? (w - 1) * LAYER_STRIDE : 0) + col * PADK;
        const int wr0  = w * LAYER_STRIDE + col * PADK + g * 4;
        const int wr1  = w * LAYER_STRIDE + col * PADK + 16;
        uint2 pw = make_uint2(0u, 0u), qw = pw;   // h[t-1] f16 == next B1
        int p_up = 0, p_dn = 0;
        for (int t = 0; t < T_; ++t) {
            const int sc = (t & (DEPTH - 1)) * SLOT_STRIDE;
            const f16x4 b1k0 = __builtin_bit_cast(f16x4, pw);  // D->B identity
            const f16x4 b1k1 = __builtin_bit_cast(f16x4, qw);
            f16x4 b0t0, b0t1;
            if (w == 0) {
                b0t0 = xp0; b0t1 = zh;
                xp0 = xp1; xp1 = xp2; xp2 = xp3;
                if (t + 4 < T_) {   // refill = time t+4 (4-slot ring, 1/iter)
                    const float* xq = x + ((size_t)(bg + col) * T_ + t + 4) * D_;
                    xp3 = pack_x4h(LD4(xq), LD4(xq + 4), g);
                }
            } else {
                if (p_up < t + 1) p_up = wait_ge_ret(&prog[w - 1], t + 1);
                const unsigned short* rp = hb + sc + rdB0;
                b0t0 = __builtin_bit_cast(f16x4,
                        *reinterpret_cast<const uint2*>(rp + g * 4));
                b0t1 = (g == 0) ? __builtin_bit_cast(f16x4,
                        *reinterpret_cast<const uint2*>(rp + 16)) : zh;
            }
            // 8 MFMA (6 for w==0): two 3-4 deep chains
            f32x4 acc0 = mfma16h(iA0, b0t0, bias0);
            f32x4 acc1 = mfma16h(iA1, b0t0, bias1);
            if (w != 0) {           // wave-uniform
                acc0 = mfma16h(iB0, b0t1, acc0);
                acc1 = mfma16h(iB1, b0t1, acc1);
            }
            acc0 = mfma16h(hA0, b1k0, acc0);
            acc1 = mfma16h(hA1, b1k0, acc1);
            acc0 = mfma16h(hB0, b1k1, acc0);
            acc1 = mfma16h(hB1, b1k1, acc1);
            pw.x = pack2h(tanh_fast(acc0[0]), tanh_fast(acc0[1]));
            pw.y = pack2h(tanh_fast(acc0[2]), tanh_fast(acc0[3]));
            qw.x = pack2h(tanh_fast(acc1[0]), tanh_fast(acc1[1]));
            qw.y = pack2h(tanh_fast(acc1[2]), tanh_fast(acc1[3]));
            // WAR: slot sc reused from t-DEPTH
            if (t >= DEPTH && p_dn < t - DEPTH + 1)
                p_dn = wait_ge_ret(&prog[w + 1], t - DEPTH + 1);
            *reinterpret_cast<uint2*>(hb + sc + wr0) = pw;
            if (g == 0) *reinterpret_cast<uint2*>(hb + sc + wr1) = qw;
            if (l == 0) publish(&prog[w], t + 1);
        }
    } else {
        // head wave: y[t] from h[9][t]
        const int rdH = (L_ - 1) * LAYER_STRIDE + col * PADK;
        int p_up = 0;
        for (int t = 0; t < T_; ++t) {
            if (p_up < t + 1) p_up = wait_ge_ret(&prog[L_ - 1], t + 1);
            const unsigned short* rp =
                hb + (t & (DEPTH - 1)) * SLOT_STRIDE + rdH;
            f16x4 bt0 = __builtin_bit_cast(f16x4,
                    *reinterpret_cast<const uint2*>(rp + g * 4));
            f16x4 bt1 = (g == 0) ? __builtin_bit_cast(f16x4,
                    *reinterpret_cast<const uint2*>(rp + 16)) : zh;
            f32x4 z0 = mfma16h(iA0, bt0, bias0);
            f32x4 z1 = mfma16h(iA1, bt0, bias1);
            z0 = mfma16h(iB0, bt1, z0);
            z1 = mfma16h(iB1, bt1, z1);
            float part = 0.f;
            #pragma unroll
            for (int r = 0; r < 4; ++r) {
                part = fmaf(l2v0[r], fmaxf(z0[r], 0.f), part);
                part = fmaf(l2v1[r], fmaxf(z1[r], 0.f), part);
            }
            part += __shfl_xor(part, 16);
            part += __shfl_xor(part, 32);
            if (l < NG) out[(size_t)(bg + l) * T_ + t] = part + l2bv;
            if (l == 0) publish(&prog[L_], t + 1);  // "h[9][t] read done"
        }
    }
}

}  // namespace

extern "C" void kernel_launch(void* const* d_in, const int* in_sizes, int n_in,
                              void* d_out, int out_size, void* d_ws, size_t ws_size,
                              hipStream_t stream) {
    const float* x     = (const float*)d_in[0];
    const float* w_ih0 = (const float*)d_in[1];
    const float* w_ih  = (const float*)d_in[2];
    const float* w_hh  = (const float*)d_in[3];
    const float* b_ih  = (const float*)d_in[4];
    const float* b_hh  = (const float*)d_in[5];
    const float* fc_w  = (const float*)d_in[6];
    const float* fc_b  = (const float*)d_in[7];
    const float* l2_w  = (const float*)d_in[8];
    const float* l2_b  = (const float*)d_in[9];
    float* out = (float*)d_out;

    const int grid = B_ / NG;  // 128
    hipLaunchKernelGGL(rnn_async, dim3(grid), dim3(NTHR), 0, stream,
                       x, w_ih0, w_ih, w_hh, b_ih, b_hh, fc_w, fc_b,
                       l2_w, l2_b, out);
}